// Round 1
// 190.432 us; speedup vs baseline: 1.0256x; 1.0256x over previous
//
#include <hip/hip_runtime.h>

// SGE-style gate: B=64, C=512, HW=784, G=8, cpg=64. One block per (b,g).
//
// R4 theory: previous 1024-thr version was MLP/latency-bound, not BW-bound
// (hbm 28%, VALU 6%): ~100 regs/wave (AGPR-parked tile) -> 1 block/CU, and
// 13 float4 in flight/wave -> 3.3KB/CU outstanding vs ~9.2KB needed
// (Little's law @900cy, 24.6GB/s per-CU share) -> 2.3TB/s load phase ==
// measured. Fix: 256-thr blocks, 49 float4/thread (784 = 4thr x 49 x 4,
// no tail), __launch_bounds__(256,2): 196+~40 regs fits the 256 budget,
// 2 blocks/CU co-resident (LDS 2x50.2KB) -> 6.3KB/CU in flight + cross-block
// overlap of load/store with reduction phases.
//
// Thread map: t = c*4 + j (c=0..63 channel, j=0..3). Thread owns float4
// columns q = j + 4k, k=0..48 (196 float4/row exactly).
// Loads/stores: single base + imm offsets (k*64B <= 3072 < 4096).

#define HW    784
#define HW4   196
#define NG    8
#define K4    49

__global__ __launch_bounds__(256, 2)
void sge_kernel(const float* __restrict__ x,
                const float* __restrict__ weight,
                const float* __restrict__ bias,
                float* __restrict__ out) {
    __shared__ float sbuf[16 * HW];   // 16 partial rows of s; row 0 reused for gate
    __shared__ float redbuf[8];

    const int t    = threadIdx.x;     // 0..255
    const int lane = t & 63;
    const int wave = t >> 6;          // 0..3
    const int j    = t & 3;           // float4 column phase

    const int bg = blockIdx.x;        // b*8 + g
    const int g  = bg & (NG - 1);
    const size_t base4 = (size_t)bg * (64 * HW4) + (size_t)(t >> 2) * HW4;

    // ---- single HBM read of the tile into registers (49 float4 = 196 VGPR) ----
    const float4* xp = (const float4*)x + base4;
    float4 v[K4];
#pragma unroll
    for (int k = 0; k < K4; ++k) v[k] = xp[j + 4 * k];
    // Pin: forbid rematerialization (re-load) of the tile in the epilogue.
#pragma unroll
    for (int k = 0; k < K4; ++k)
        asm volatile("" : "+v"(v[k].x), "+v"(v[k].y), "+v"(v[k].z), "+v"(v[k].w));

    // ---- per-channel spatial mean (4 threads/channel, intra-wave) ----
    float cs = 0.f;
#pragma unroll
    for (int k = 0; k < K4; ++k) cs += (v[k].x + v[k].y) + (v[k].z + v[k].w);
    cs += __shfl_xor(cs, 1, 64);
    cs += __shfl_xor(cs, 2, 64);
    const float mean_c = cs * (1.0f / (float)HW);

    // ---- s partials: w = v*mean_c, reduced over 4-channel groups ----
    // wave w covers channels 16w..16w+15; group g4 = lane>>4 covers 4 channels.
    // After shfl_xor 4,8 lanes with ((lane>>2)&3)==0 hold the group sum.
    const int  row    = (wave << 2) + (lane >> 4);     // 0..15
    float4*    srow   = (float4*)(sbuf + row * HW);
    const bool writer = ((lane >> 2) & 3) == 0;        // 16 writer lanes/wave
#pragma unroll
    for (int k = 0; k < K4; ++k) {
        float4 w;
        w.x = v[k].x * mean_c; w.y = v[k].y * mean_c;
        w.z = v[k].z * mean_c; w.w = v[k].w * mean_c;
        w.x += __shfl_xor(w.x, 4, 64);  w.x += __shfl_xor(w.x, 8, 64);
        w.y += __shfl_xor(w.y, 4, 64);  w.y += __shfl_xor(w.y, 8, 64);
        w.z += __shfl_xor(w.z, 4, 64);  w.z += __shfl_xor(w.z, 8, 64);
        w.w += __shfl_xor(w.w, 4, 64);  w.w += __shfl_xor(w.w, 8, 64);
        if (writer) srow[j + 4 * k] = w;
    }
    __syncthreads();

    // ---- cross-row sum: thread owns p = t, t+256, t+512 (+768 if t<16) ----
    float s0 = 0.f, s1 = 0.f, s2 = 0.f, s3 = 0.f;
#pragma unroll
    for (int r = 0; r < 16; ++r) {
        const float* rw = sbuf + r * HW;
        s0 += rw[t];
        s1 += rw[t + 256];
        s2 += rw[t + 512];
        if (t < 16) s3 += rw[t + 768];
    }

    // ---- block reduction for mu, var ----
    float rs  = s0 + s1 + s2 + s3;
    float rs2 = s0 * s0 + s1 * s1 + s2 * s2 + s3 * s3;
#pragma unroll
    for (int m = 1; m < 64; m <<= 1) {
        rs  += __shfl_xor(rs,  m, 64);
        rs2 += __shfl_xor(rs2, m, 64);
    }
    if (lane == 0) { redbuf[wave] = rs; redbuf[4 + wave] = rs2; }
    __syncthreads();

    const float sum_s  = redbuf[0] + redbuf[1] + redbuf[2] + redbuf[3];
    const float sum_s2 = redbuf[4] + redbuf[5] + redbuf[6] + redbuf[7];
    const float mu   = sum_s * (1.0f / (float)HW);
    const float var  = sum_s2 * (1.0f / (float)HW) - mu * mu;
    const float rstd = rsqrtf(var + 1e-5f);
    const float wg   = weight[g];
    const float bgv  = bias[g];

    // ---- gate into sbuf[0..783] (row 0; its partials were consumed pre-barrier) ----
    {
        const float z0 = (s0 - mu) * rstd * wg + bgv;
        const float z1 = (s1 - mu) * rstd * wg + bgv;
        const float z2 = (s2 - mu) * rstd * wg + bgv;
        sbuf[t]       = 1.0f / (1.0f + __expf(-z0));
        sbuf[t + 256] = 1.0f / (1.0f + __expf(-z1));
        sbuf[t + 512] = 1.0f / (1.0f + __expf(-z2));
        if (t < 16) {
            const float z3 = (s3 - mu) * rstd * wg + bgv;
            sbuf[t + 768] = 1.0f / (1.0f + __expf(-z3));
        }
    }
    __syncthreads();

    // ---- epilogue: out = v * gate (gate via LDS float4 broadcast) ----
    const float4* gate4 = (const float4*)sbuf;
    float4* op = (float4*)out + base4;
#pragma unroll
    for (int k = 0; k < K4; ++k) {
        const float4 gv = gate4[j + 4 * k];
        float4 o;
        o.x = v[k].x * gv.x; o.y = v[k].y * gv.y;
        o.z = v[k].z * gv.z; o.w = v[k].w * gv.w;
        op[j + 4 * k] = o;
    }
}

extern "C" void kernel_launch(void* const* d_in, const int* in_sizes, int n_in,
                              void* d_out, int out_size, void* d_ws, size_t ws_size,
                              hipStream_t stream) {
    const float* x      = (const float*)d_in[0];
    const float* weight = (const float*)d_in[1];
    const float* bias   = (const float*)d_in[2];
    float* out = (float*)d_out;
    sge_kernel<<<dim3(512), dim3(256), 0, stream>>>(x, weight, bias, out);
}